// Round 17
// baseline (1946.346 us; speedup 1.0000x reference)
//
#include <hip/hip_runtime.h>
#include <hip/hip_bf16.h>

#define T_STEPS 128
#define B_SZ    1024
#define IN_SZ   47
#define H_SZ    646
#define OUT_SZ  5

#define XK    96      // xs padded row stride (47 -> 96)
#define K0    768     // layer0 K = 96 + 672
#define K1    1344    // layer1 K = 672 + 672 (also the state-slab row stride)
#define N0PAD 704     // L0 packed-W cols (11 * 64, zero-padded)
#define N1PAD 672     // L1 packed-W cols
#define RING  17      // RING=6 L2-resident ring falsified (r15 3310us fenced,
                      // r16 4423us XCD-pinned): tighter WAR coupling + L2
                      // thrash. 17-slot MALL-resident ring is the fast design.
#define SLAB  172032  // 128 rows * 1344 cols, elements per rg slab
#define FSTR  256     // flag GROUP stride (ints); per-publisher slots
#define SLOT  16      // ints between publisher slots (64B, no line sharing)

// tiles (r11-proven): L0 96-col x7 blocks, L1 48-col x14 blocks
#define NL0B  7
#define NL1B  14
#define NBLK  (8 * (NL0B + NL1B))   // 168

typedef __hip_bfloat16 bf16;
typedef unsigned short ush;
using frag8 = __attribute__((ext_vector_type(8))) short;  // 8 bf16
using f32x4 = __attribute__((ext_vector_type(4))) float;

// ---------------------------------------------------------------- prep kernels

__global__ void prep_xs(const float* __restrict__ xs, bf16* __restrict__ xs_pad) {
    int idx = blockIdx.x * blockDim.x + threadIdx.x;
    if (idx >= T_STEPS * B_SZ * XK) return;
    int k = idx % XK;
    int rb = idx / XK;
    float v = (k < IN_SZ) ? xs[(size_t)rb * IN_SZ + k] : 0.f;
    xs_pad[idx] = __float2bfloat16(v);
}

__global__ void pack_w0(const float* __restrict__ Wih, const float* __restrict__ Whh,
                        bf16* __restrict__ Wc) {
    int idx = blockIdx.x * blockDim.x + threadIdx.x;
    if (idx >= N0PAD * K0) return;
    int j = idx / K0, k = idx % K0;
    float v = 0.f;
    if (j < H_SZ) {
        if (k < IN_SZ)                      v = Wih[(size_t)j * IN_SZ + k];
        else if (k >= XK && k < XK + H_SZ)  v = Whh[(size_t)j * H_SZ + (k - XK)];
    }
    Wc[idx] = __float2bfloat16(v);
}

__global__ void pack_w1(const float* __restrict__ Wih, const float* __restrict__ Whh,
                        bf16* __restrict__ Wc) {
    int idx = blockIdx.x * blockDim.x + threadIdx.x;
    if (idx >= N1PAD * K1) return;
    int j = idx / K1, k = idx % K1;
    float v = 0.f;
    if (j < H_SZ) {
        if (k < H_SZ)                          v = Wih[(size_t)j * H_SZ + k];
        else if (k >= 672 && k < 672 + H_SZ)   v = Whh[(size_t)j * H_SZ + (k - 672)];
    }
    Wc[idx] = __float2bfloat16(v);
}

__global__ void pack_bias(const float* __restrict__ bi, const float* __restrict__ bh,
                          float* __restrict__ b, int n) {
    int j = blockIdx.x * blockDim.x + threadIdx.x;
    if (j >= n) return;
    b[j] = (j < H_SZ) ? (bi[j] + bh[j]) : 0.f;
}

// ---------------------------------------------------------------- persistent RNN
// r22 — r18 structure (replay-proven block-barrier protocol, per-publisher
// flag slots, lane-parallel polls, 17-slot ring) with ONE change:
// NON-TEMPORAL h-state stores.
// Rationale: 6 protocol variants cluster at ~1.5ms while instruction-level
// hop models sum to 2-4us/hop vs 11.7us measured. The unmodeled term is the
// max-over-edges tail of serving lines DIRTY in another L2 / in writeback
// transit (FETCH 204MB vs 6.2GB demand shows reads mostly hit locally, but
// the chain gates on the slowest edge each hop). nt stores write through to
// the MALL coherence point without allocating dirty L2 lines: (a) state is
// globally visible BEFORE the flag publishes (also tightens the r14-style
// race window), (b) write-allocate RMW fetches vanish. Cost: same-XCD
// readers lose L2 hits -> MALL reads (~650cy, pipelined). Diagnostic
// signature nt took effect: FETCH_SIZE 204MB -> multi-GB.
// Session knowledge: RING=6 falsified (r15/r16); per-step fences cost
// +14us/step (r15); flag RMW decontention neutral (r18); barrier-free
// wave-granular protocol racy (r20) — WITHDRAWN; VGPR pin no gain (r20).

__device__ __forceinline__ void tanh_store(ush* dst, float x) {
    x = fminf(fmaxf(x, -15.f), 15.f);
    float e = __expf(2.f * x);
    bf16 hb = __float2bfloat16((e - 1.f) / (e + 1.f));
    __builtin_nontemporal_store(*(ush*)&hb, dst);   // r22: write-through, no
                                                    // dirty-L2 stranding
}

__device__ __forceinline__ void poll_ge(int* p, int need) {
    while (__hip_atomic_load(p, __ATOMIC_RELAXED, __HIP_MEMORY_SCOPE_AGENT) < need)
        __builtin_amdgcn_s_sleep(2);
}

__global__ __launch_bounds__(512, 2) void persist(
    const bf16* __restrict__ xs_pad, const bf16* __restrict__ Wc0,
    const bf16* __restrict__ Wc1, const float* __restrict__ b0,
    const float* __restrict__ b1, bf16* __restrict__ Sring,
    int* __restrict__ flags)
{
    extern __shared__ ush Wlds[];
    const int bid  = blockIdx.x;
    const int rg   = bid & 7;
    const int c8   = bid >> 3;
    const bool isL0 = (c8 < NL0B);
    const int tid  = threadIdx.x;
    const int wv   = tid >> 6;
    const int lane = tid & 63;
    const int q8   = (lane >> 4) * 8;    // fragment k offset (elements)
    const int l15  = lane & 15;

    // ---- stage W slice into LDS in fragment order (once) ----
    if (isL0) {
        const int col0 = c8 * 96;
        for (int g = wv; g < 144; g += 8) {           // g = kc*6 + ct
            int kc = g / 6, ct = g % 6;
            const bf16* src = Wc0 + (size_t)(col0 + ct*16 + l15) * K0 + kc*32 + q8;
            *(uint4*)&Wlds[g*512 + lane*8] = *(const uint4*)src;
        }
    } else {
        const int col0 = (c8 - NL0B) * 48;
        for (int g = wv; g < 126; g += 8) {           // g = kc*3 + ct
            int kc = g / 3, ct = g % 3;
            const bf16* src = Wc1 + (size_t)(col0 + ct*16 + l15) * K1 + kc*32 + q8;
            *(uint4*)&Wlds[g*512 + lane*8] = *(const uint4*)src;
        }
    }
    __syncthreads();

    const int loc = wv * 16 + l15;      // this wave's A-fragment row (16 rows/wave)
    bf16* const ringbase = Sring + (size_t)rg * RING * SLAB;
    int*  const fL0 = flags + rg * FSTR;          // NL0B publisher slots (SLOT apart)
    int*  const fL1 = flags + (8 + rg) * FSTR;    // NL1B publisher slots

    if (isL0) {
        const int col0 = c8 * 96;
        float bias[6];
        #pragma unroll
        for (int ct = 0; ct < 6; ++ct) bias[ct] = b0[col0 + ct*16 + l15];

        for (int p = 0; p < 128; ++p) {
            const bf16* rsl = ringbase + (size_t)((p + RING - 1) % RING) * SLAB;
            bf16*       wsl = ringbase + (size_t)(p % RING) * SLAB;

            // xs chunks: input-static, issue before any wait
            const bf16* xr = xs_pad + ((size_t)p * B_SZ + rg*128 + loc) * XK + q8;
            uint4 xbuf[3];
            #pragma unroll
            for (int i = 0; i < 3; ++i) xbuf[i] = *(const uint4*)(xr + i*32);

            // parallel poll: lanes 0..6 watch L0 slots; lanes 16..29 watch L1
            // slots (WAR). One converged loop -> all slots observed in parallel.
            if (wv == 0) {
                int* addr = nullptr; int need = 0;
                if (p > 0 && lane < NL0B)            { addr = &fL0[lane * SLOT];        need = p; }
                else if (p >= RING && lane >= 16 && lane < 16 + NL1B)
                                                     { addr = &fL1[(lane - 16) * SLOT]; need = p - 16; }
                if (addr) poll_ge(addr, need);
            }
            __syncthreads();
            if (p >= RING + 1 && (p - 1) % RING == 0)
                __builtin_amdgcn_fence(__ATOMIC_ACQUIRE, "agent");

            // A = [x_t(96) | h0(p-1)(672)], C = h0(p) -> slab cols [0,672)
            const bf16* hr = rsl + (size_t)loc * K1 + q8;
            uint4 hbuf[21];
            #pragma unroll
            for (int i = 0; i < 21; ++i) hbuf[i] = *(const uint4*)(hr + i*32);

            f32x4 acc[6] = {};
            #pragma unroll
            for (int kc = 0; kc < 24; ++kc) {
                frag8 af = (kc < 3) ? *(const frag8*)&xbuf[kc]
                                    : *(const frag8*)&hbuf[kc-3];
                #pragma unroll
                for (int ct = 0; ct < 6; ++ct) {
                    frag8 wf = *(const frag8*)&Wlds[(kc*6+ct)*512 + lane*8];
                    acc[ct] = __builtin_amdgcn_mfma_f32_16x16x32_bf16(
                        af, wf, acc[ct], 0, 0, 0);
                }
            }
            const int rbase = wv*16 + (lane>>4)*4;
            #pragma unroll
            for (int ct = 0; ct < 6; ++ct) {
                const int col = col0 + ct*16 + l15;
                if (col < H_SZ) {
                    #pragma unroll
                    for (int i = 0; i < 4; ++i)
                        tanh_store((ush*)(wsl + (size_t)(rbase+i)*K1 + col),
                                   acc[ct][i] + bias[ct]);
                }
            }
            __syncthreads();   // per-wave vmcnt(0) drain: stores at MALL pre-publish
            if (tid == 0)
                __hip_atomic_store(&fL0[c8 * SLOT], p + 1, __ATOMIC_RELAXED,
                                   __HIP_MEMORY_SCOPE_AGENT);
        }
    } else {
        const int col0 = (c8 - NL0B) * 48;
        const int myslot = (c8 - NL0B) * SLOT;
        float bias[3];
        #pragma unroll
        for (int ct = 0; ct < 3; ++ct) bias[ct] = b1[col0 + ct*16 + l15];

        for (int q = 1; q <= 128; ++q) {
            const bf16* rsl = ringbase + (size_t)((q + RING - 1) % RING) * SLAB;
            bf16*       wsl = ringbase + (size_t)(q % RING) * SLAB;
            const bf16* ar  = rsl + (size_t)loc * K1 + q8;

            // ---- stage 1: h0 half (gated only by fL0; L0 runs ~15 ahead) ----
            if (wv == 0 && lane < NL0B) poll_ge(&fL0[lane * SLOT], q);
            __syncthreads();
            if (q >= RING + 1 && (q - 1) % RING == 0)
                __builtin_amdgcn_fence(__ATOMIC_ACQUIRE, "agent");

            uint4 h0buf[21];
            #pragma unroll
            for (int i = 0; i < 21; ++i) h0buf[i] = *(const uint4*)(ar + i*32);
            f32x4 acc[3] = {};
            #pragma unroll
            for (int kc = 0; kc < 21; ++kc) {
                frag8 af = *(const frag8*)&h0buf[kc];
                #pragma unroll
                for (int ct = 0; ct < 3; ++ct) {
                    frag8 wf = *(const frag8*)&Wlds[(kc*3+ct)*512 + lane*8];
                    acc[ct] = __builtin_amdgcn_mfma_f32_16x16x32_bf16(
                        af, wf, acc[ct], 0, 0, 0);
                }
            }

            // ---- stage 2: h1 half (the true serial gate, polled LATE) ----
            if (q > 1) {
                if (wv == 0 && lane < NL1B) poll_ge(&fL1[lane * SLOT], q - 1);
                __syncthreads();
            }
            uint4 h1buf[21];
            #pragma unroll
            for (int i = 0; i < 21; ++i)
                h1buf[i] = *(const uint4*)(ar + (21 + i)*32);
            #pragma unroll
            for (int kc = 21; kc < 42; ++kc) {
                frag8 af = *(const frag8*)&h1buf[kc-21];
                #pragma unroll
                for (int ct = 0; ct < 3; ++ct) {
                    frag8 wf = *(const frag8*)&Wlds[(kc*3+ct)*512 + lane*8];
                    acc[ct] = __builtin_amdgcn_mfma_f32_16x16x32_bf16(
                        af, wf, acc[ct], 0, 0, 0);
                }
            }
            const int rbase = wv*16 + (lane>>4)*4;
            #pragma unroll
            for (int ct = 0; ct < 3; ++ct) {
                const int col = col0 + ct*16 + l15;
                if (col < H_SZ) {
                    #pragma unroll
                    for (int i = 0; i < 4; ++i)
                        tanh_store((ush*)(wsl + (size_t)(rbase+i)*K1 + 672 + col),
                                   acc[ct][i] + bias[ct]);
                }
            }
            __syncthreads();   // per-wave vmcnt(0) drain: stores at MALL pre-publish
            if (tid == 0)
                __hip_atomic_store(&fL1[myslot], q, __ATOMIC_RELAXED,
                                   __HIP_MEMORY_SCOPE_AGENT);
        }
    }
}

// ---------------------------------------------------------------- classifier
__global__ __launch_bounds__(256) void classifier(
    const bf16* __restrict__ Sring, const float* __restrict__ Wout,
    const float* __restrict__ bout, float* __restrict__ out)
{
    const int wave = threadIdx.x >> 6, lane = threadIdx.x & 63;
    const int row = blockIdx.x * 4 + wave;
    const int rg = row >> 7, loc = row & 127;
    const bf16* h1 = Sring + ((size_t)rg * RING + (128 % RING)) * SLAB
                     + (size_t)loc * K1 + 672;
    float acc[OUT_SZ] = {0.f, 0.f, 0.f, 0.f, 0.f};
    for (int k = lane; k < H_SZ; k += 64) {
        float h = __bfloat162float(h1[k]);
        #pragma unroll
        for (int o = 0; o < OUT_SZ; ++o) acc[o] += h * Wout[(size_t)o * H_SZ + k];
    }
    #pragma unroll
    for (int o = 0; o < OUT_SZ; ++o) {
        float v = acc[o];
        #pragma unroll
        for (int off = 32; off; off >>= 1) v += __shfl_down(v, off, 64);
        if (lane == 0) out[(size_t)row * OUT_SZ + o] = v + bout[o];
    }
}

// ---------------------------------------------------------------- launch

extern "C" void kernel_launch(void* const* d_in, const int* in_sizes, int n_in,
                              void* d_out, int out_size, void* d_ws, size_t ws_size,
                              hipStream_t stream) {
    const float* xs   = (const float*)d_in[0];
    const float* Wih0 = (const float*)d_in[1];
    const float* Whh0 = (const float*)d_in[2];
    const float* bih0 = (const float*)d_in[3];
    const float* bhh0 = (const float*)d_in[4];
    const float* Wih1 = (const float*)d_in[5];
    const float* Whh1 = (const float*)d_in[6];
    const float* bih1 = (const float*)d_in[7];
    const float* bhh1 = (const float*)d_in[8];
    const float* Wout = (const float*)d_in[9];
    const float* bout = (const float*)d_in[10];
    float* out = (float*)d_out;

    char* ws = (char*)d_ws;
    size_t off = 0;
    bf16* xs_pad = (bf16*)(ws + off); off += (size_t)T_STEPS * B_SZ * XK * 2;
    bf16* Wc0    = (bf16*)(ws + off); off += (size_t)N0PAD * K0 * 2;
    bf16* Wc1    = (bf16*)(ws + off); off += (size_t)N1PAD * K1 * 2;
    float* b0    = (float*)(ws + off); off += (size_t)N0PAD * 4;
    float* b1    = (float*)(ws + off); off += (size_t)N1PAD * 4;
    bf16* Sring  = (bf16*)(ws + off); off += (size_t)8 * RING * SLAB * 2;
    int*  flags  = (int*)(ws + off);  off += (size_t)16 * FSTR * 4;

    // ring (incl. zero-state slots + pad columns) and all flag slots start zero
    hipMemsetAsync(Sring, 0, (size_t)8 * RING * SLAB * 2, stream);
    hipMemsetAsync(flags, 0, (size_t)16 * FSTR * 4, stream);

    prep_xs <<<(T_STEPS * B_SZ * XK + 255) / 256, 256, 0, stream>>>(xs, xs_pad);
    pack_w0 <<<(N0PAD * K0 + 255) / 256, 256, 0, stream>>>(Wih0, Whh0, Wc0);
    pack_w1 <<<(N1PAD * K1 + 255) / 256, 256, 0, stream>>>(Wih1, Whh1, Wc1);
    pack_bias<<<(N0PAD + 255) / 256, 256, 0, stream>>>(bih0, bhh0, b0, N0PAD);
    pack_bias<<<(N1PAD + 255) / 256, 256, 0, stream>>>(bih1, bhh1, b1, N1PAD);

    // dynamic LDS: max(W0 slice 147456 B, W1 slice 129024 B)
    hipFuncSetAttribute((const void*)persist,
                        hipFuncAttributeMaxDynamicSharedMemorySize, 147456);
    void* args[] = { (void*)&xs_pad, (void*)&Wc0, (void*)&Wc1, (void*)&b0,
                     (void*)&b1, (void*)&Sring, (void*)&flags };
    hipLaunchCooperativeKernel((const void*)persist, dim3(NBLK), dim3(512),
                               args, 147456, stream);

    classifier<<<B_SZ / 4, 256, 0, stream>>>(Sring, Wout, bout, out);
}

// Round 22
// 1610.529 us; speedup vs baseline: 1.2085x; 1.2085x over previous
//
#include <hip/hip_runtime.h>
#include <hip/hip_bf16.h>

#define T_STEPS 128
#define B_SZ    1024
#define IN_SZ   47
#define H_SZ    646
#define OUT_SZ  5

#define XK    96      // xs padded row stride (47 -> 96)
#define K0    768     // layer0 K = 96 + 672
#define K1    1344    // layer1 K = 672 + 672 (also the state-slab row stride)
#define N0PAD 704     // L0 packed-W cols (11 * 64, zero-padded)
#define N1PAD 672     // L1 packed-W cols
#define RING  17      // RING=6 L2-resident ring falsified (r15 3310us fenced,
                      // r16 4423us XCD-pinned). 17-slot MALL-resident ring +
                      // spread readers + fresh-address eviction is fastest.
#define SLAB  172032  // 128 rows * 1344 cols, elements per rg slab
#define FSTR  256     // flag GROUP stride (ints); per-publisher slots
#define SLOT  16      // ints between publisher slots (64B, no line sharing)

// tiles (r11-proven): L0 96-col x7 blocks, L1 48-col x14 blocks
#define NL0B  7
#define NL1B  14
#define NBLK  (8 * (NL0B + NL1B))   // 168

typedef __hip_bfloat16 bf16;
typedef unsigned short ush;
using frag8 = __attribute__((ext_vector_type(8))) short;  // 8 bf16
using f32x4 = __attribute__((ext_vector_type(4))) float;

// ---------------------------------------------------------------- prep kernels

__global__ void prep_xs(const float* __restrict__ xs, bf16* __restrict__ xs_pad) {
    int idx = blockIdx.x * blockDim.x + threadIdx.x;
    if (idx >= T_STEPS * B_SZ * XK) return;
    int k = idx % XK;
    int rb = idx / XK;
    float v = (k < IN_SZ) ? xs[(size_t)rb * IN_SZ + k] : 0.f;
    xs_pad[idx] = __float2bfloat16(v);
}

__global__ void pack_w0(const float* __restrict__ Wih, const float* __restrict__ Whh,
                        bf16* __restrict__ Wc) {
    int idx = blockIdx.x * blockDim.x + threadIdx.x;
    if (idx >= N0PAD * K0) return;
    int j = idx / K0, k = idx % K0;
    float v = 0.f;
    if (j < H_SZ) {
        if (k < IN_SZ)                      v = Wih[(size_t)j * IN_SZ + k];
        else if (k >= XK && k < XK + H_SZ)  v = Whh[(size_t)j * H_SZ + (k - XK)];
    }
    Wc[idx] = __float2bfloat16(v);
}

__global__ void pack_w1(const float* __restrict__ Wih, const float* __restrict__ Whh,
                        bf16* __restrict__ Wc) {
    int idx = blockIdx.x * blockDim.x + threadIdx.x;
    if (idx >= N1PAD * K1) return;
    int j = idx / K1, k = idx % K1;
    float v = 0.f;
    if (j < H_SZ) {
        if (k < H_SZ)                          v = Wih[(size_t)j * H_SZ + k];
        else if (k >= 672 && k < 672 + H_SZ)   v = Whh[(size_t)j * H_SZ + (k - 672)];
    }
    Wc[idx] = __float2bfloat16(v);
}

__global__ void pack_bias(const float* __restrict__ bi, const float* __restrict__ bh,
                          float* __restrict__ b, int n) {
    int j = blockIdx.x * blockDim.x + threadIdx.x;
    if (j >= n) return;
    b[j] = (j < H_SZ) ? (bi[j] + bh[j]) : 0.f;
}

// ---------------------------------------------------------------- persistent RNN
// FINAL == r18 (best harness-verified: 1607us, round 8; replay-proven).
// Session ledger — all single-variable probes from this structure, measured
// on MI355X:
//  * RING=6 L2-resident ring: 2-3x SLOWER (r15 fenced 3310us, r16 pinned
//    4423us) — concentrating 21 streaming readers thrashes one 4MB L2.
//  * per-step agent acquire/release fences: +14us/step (r15) — wbl2 drains.
//  * flag RMW decontention + lane-parallel polls: neutral (r18, kept).
//  * wave-granular barrier-free protocol: neutral AND intermittently racy
//    (r20 post-timing divergence) — WITHDRAWN.
//  * VGPR pin via waves_per_eu: no gain (r20).
//  * NON-TEMPORAL h stores: +315us (r22) — WRITE_SIZE 337->655MB (partial-
//    line write-through), FETCH unchanged (no dirty-line tail existed);
//    store-ack latency moved ONTO the serial chain's pre-publish drain.
// Net: the ~11.7us/step hop is invariant to state placement, flag
// contention, barrier granularity, and register budget. The column-split
// decomposition's per-step all-to-all exchange through MALL is the floor
// at ~1.5ms; per-instruction models give ~3us/hop, so the residual is
// unattributed memory-system latency — needs disasm/latency probes beyond
// this harness to attack further.
// Structure: r13 skeleton (column tiles, W-in-LDS, plain dirty-L2 h-state
// stores, 17-slot ring, per-wrap agent-acquire fence, publish after
// __syncthreads vmcnt drain) + L1 h0-before-h1 critical-path order +
// per-publisher flag slots with lane-parallel observation.

__device__ __forceinline__ void tanh_store(ush* dst, float x) {
    x = fminf(fmaxf(x, -15.f), 15.f);
    float e = __expf(2.f * x);
    bf16 hb = __float2bfloat16((e - 1.f) / (e + 1.f));
    *dst = *(ush*)&hb;     // plain store: coalesced, dirty in local (XCD) L2
}

__device__ __forceinline__ void poll_ge(int* p, int need) {
    while (__hip_atomic_load(p, __ATOMIC_RELAXED, __HIP_MEMORY_SCOPE_AGENT) < need)
        __builtin_amdgcn_s_sleep(2);
}

__global__ __launch_bounds__(512, 2) void persist(
    const bf16* __restrict__ xs_pad, const bf16* __restrict__ Wc0,
    const bf16* __restrict__ Wc1, const float* __restrict__ b0,
    const float* __restrict__ b1, bf16* __restrict__ Sring,
    int* __restrict__ flags)
{
    extern __shared__ ush Wlds[];
    const int bid  = blockIdx.x;
    const int rg   = bid & 7;
    const int c8   = bid >> 3;
    const bool isL0 = (c8 < NL0B);
    const int tid  = threadIdx.x;
    const int wv   = tid >> 6;
    const int lane = tid & 63;
    const int q8   = (lane >> 4) * 8;    // fragment k offset (elements)
    const int l15  = lane & 15;

    // ---- stage W slice into LDS in fragment order (once) ----
    if (isL0) {
        const int col0 = c8 * 96;
        for (int g = wv; g < 144; g += 8) {           // g = kc*6 + ct
            int kc = g / 6, ct = g % 6;
            const bf16* src = Wc0 + (size_t)(col0 + ct*16 + l15) * K0 + kc*32 + q8;
            *(uint4*)&Wlds[g*512 + lane*8] = *(const uint4*)src;
        }
    } else {
        const int col0 = (c8 - NL0B) * 48;
        for (int g = wv; g < 126; g += 8) {           // g = kc*3 + ct
            int kc = g / 3, ct = g % 3;
            const bf16* src = Wc1 + (size_t)(col0 + ct*16 + l15) * K1 + kc*32 + q8;
            *(uint4*)&Wlds[g*512 + lane*8] = *(const uint4*)src;
        }
    }
    __syncthreads();

    const int loc = wv * 16 + l15;      // this wave's A-fragment row (16 rows/wave)
    bf16* const ringbase = Sring + (size_t)rg * RING * SLAB;
    int*  const fL0 = flags + rg * FSTR;          // NL0B publisher slots (SLOT apart)
    int*  const fL1 = flags + (8 + rg) * FSTR;    // NL1B publisher slots

    if (isL0) {
        const int col0 = c8 * 96;
        float bias[6];
        #pragma unroll
        for (int ct = 0; ct < 6; ++ct) bias[ct] = b0[col0 + ct*16 + l15];

        for (int p = 0; p < 128; ++p) {
            const bf16* rsl = ringbase + (size_t)((p + RING - 1) % RING) * SLAB;
            bf16*       wsl = ringbase + (size_t)(p % RING) * SLAB;

            // xs chunks: input-static, issue before any wait
            const bf16* xr = xs_pad + ((size_t)p * B_SZ + rg*128 + loc) * XK + q8;
            uint4 xbuf[3];
            #pragma unroll
            for (int i = 0; i < 3; ++i) xbuf[i] = *(const uint4*)(xr + i*32);

            // parallel poll: lanes 0..6 watch L0 slots; lanes 16..29 watch L1
            // slots (WAR). One converged loop -> all slots observed in parallel.
            if (wv == 0) {
                int* addr = nullptr; int need = 0;
                if (p > 0 && lane < NL0B)            { addr = &fL0[lane * SLOT];        need = p; }
                else if (p >= RING && lane >= 16 && lane < 16 + NL1B)
                                                     { addr = &fL1[(lane - 16) * SLOT]; need = p - 16; }
                if (addr) poll_ge(addr, need);
            }
            __syncthreads();
            if (p >= RING + 1 && (p - 1) % RING == 0)
                __builtin_amdgcn_fence(__ATOMIC_ACQUIRE, "agent");

            // A = [x_t(96) | h0(p-1)(672)], C = h0(p) -> slab cols [0,672)
            const bf16* hr = rsl + (size_t)loc * K1 + q8;
            uint4 hbuf[21];
            #pragma unroll
            for (int i = 0; i < 21; ++i) hbuf[i] = *(const uint4*)(hr + i*32);

            f32x4 acc[6] = {};
            #pragma unroll
            for (int kc = 0; kc < 24; ++kc) {
                frag8 af = (kc < 3) ? *(const frag8*)&xbuf[kc]
                                    : *(const frag8*)&hbuf[kc-3];
                #pragma unroll
                for (int ct = 0; ct < 6; ++ct) {
                    frag8 wf = *(const frag8*)&Wlds[(kc*6+ct)*512 + lane*8];
                    acc[ct] = __builtin_amdgcn_mfma_f32_16x16x32_bf16(
                        af, wf, acc[ct], 0, 0, 0);
                }
            }
            const int rbase = wv*16 + (lane>>4)*4;
            #pragma unroll
            for (int ct = 0; ct < 6; ++ct) {
                const int col = col0 + ct*16 + l15;
                if (col < H_SZ) {
                    #pragma unroll
                    for (int i = 0; i < 4; ++i)
                        tanh_store((ush*)(wsl + (size_t)(rbase+i)*K1 + col),
                                   acc[ct][i] + bias[ct]);
                }
            }
            __syncthreads();   // per-wave vmcnt(0) drain: stores in L2 pre-publish
            if (tid == 0)
                __hip_atomic_store(&fL0[c8 * SLOT], p + 1, __ATOMIC_RELAXED,
                                   __HIP_MEMORY_SCOPE_AGENT);
        }
    } else {
        const int col0 = (c8 - NL0B) * 48;
        const int myslot = (c8 - NL0B) * SLOT;
        float bias[3];
        #pragma unroll
        for (int ct = 0; ct < 3; ++ct) bias[ct] = b1[col0 + ct*16 + l15];

        for (int q = 1; q <= 128; ++q) {
            const bf16* rsl = ringbase + (size_t)((q + RING - 1) % RING) * SLAB;
            bf16*       wsl = ringbase + (size_t)(q % RING) * SLAB;
            const bf16* ar  = rsl + (size_t)loc * K1 + q8;

            // ---- stage 1: h0 half (gated only by fL0; L0 runs ~15 ahead) ----
            if (wv == 0 && lane < NL0B) poll_ge(&fL0[lane * SLOT], q);
            __syncthreads();
            if (q >= RING + 1 && (q - 1) % RING == 0)
                __builtin_amdgcn_fence(__ATOMIC_ACQUIRE, "agent");

            uint4 h0buf[21];
            #pragma unroll
            for (int i = 0; i < 21; ++i) h0buf[i] = *(const uint4*)(ar + i*32);
            f32x4 acc[3] = {};
            #pragma unroll
            for (int kc = 0; kc < 21; ++kc) {
                frag8 af = *(const frag8*)&h0buf[kc];
                #pragma unroll
                for (int ct = 0; ct < 3; ++ct) {
                    frag8 wf = *(const frag8*)&Wlds[(kc*3+ct)*512 + lane*8];
                    acc[ct] = __builtin_amdgcn_mfma_f32_16x16x32_bf16(
                        af, wf, acc[ct], 0, 0, 0);
                }
            }

            // ---- stage 2: h1 half (the true serial gate, polled LATE) ----
            if (q > 1) {
                if (wv == 0 && lane < NL1B) poll_ge(&fL1[lane * SLOT], q - 1);
                __syncthreads();
            }
            uint4 h1buf[21];
            #pragma unroll
            for (int i = 0; i < 21; ++i)
                h1buf[i] = *(const uint4*)(ar + (21 + i)*32);
            #pragma unroll
            for (int kc = 21; kc < 42; ++kc) {
                frag8 af = *(const frag8*)&h1buf[kc-21];
                #pragma unroll
                for (int ct = 0; ct < 3; ++ct) {
                    frag8 wf = *(const frag8*)&Wlds[(kc*3+ct)*512 + lane*8];
                    acc[ct] = __builtin_amdgcn_mfma_f32_16x16x32_bf16(
                        af, wf, acc[ct], 0, 0, 0);
                }
            }
            const int rbase = wv*16 + (lane>>4)*4;
            #pragma unroll
            for (int ct = 0; ct < 3; ++ct) {
                const int col = col0 + ct*16 + l15;
                if (col < H_SZ) {
                    #pragma unroll
                    for (int i = 0; i < 4; ++i)
                        tanh_store((ush*)(wsl + (size_t)(rbase+i)*K1 + 672 + col),
                                   acc[ct][i] + bias[ct]);
                }
            }
            __syncthreads();   // per-wave vmcnt(0) drain: stores in L2 pre-publish
            if (tid == 0)
                __hip_atomic_store(&fL1[myslot], q, __ATOMIC_RELAXED,
                                   __HIP_MEMORY_SCOPE_AGENT);
        }
    }
}

// ---------------------------------------------------------------- classifier
__global__ __launch_bounds__(256) void classifier(
    const bf16* __restrict__ Sring, const float* __restrict__ Wout,
    const float* __restrict__ bout, float* __restrict__ out)
{
    const int wave = threadIdx.x >> 6, lane = threadIdx.x & 63;
    const int row = blockIdx.x * 4 + wave;
    const int rg = row >> 7, loc = row & 127;
    const bf16* h1 = Sring + ((size_t)rg * RING + (128 % RING)) * SLAB
                     + (size_t)loc * K1 + 672;
    float acc[OUT_SZ] = {0.f, 0.f, 0.f, 0.f, 0.f};
    for (int k = lane; k < H_SZ; k += 64) {
        float h = __bfloat162float(h1[k]);
        #pragma unroll
        for (int o = 0; o < OUT_SZ; ++o) acc[o] += h * Wout[(size_t)o * H_SZ + k];
    }
    #pragma unroll
    for (int o = 0; o < OUT_SZ; ++o) {
        float v = acc[o];
        #pragma unroll
        for (int off = 32; off; off >>= 1) v += __shfl_down(v, off, 64);
        if (lane == 0) out[(size_t)row * OUT_SZ + o] = v + bout[o];
    }
}

// ---------------------------------------------------------------- launch

extern "C" void kernel_launch(void* const* d_in, const int* in_sizes, int n_in,
                              void* d_out, int out_size, void* d_ws, size_t ws_size,
                              hipStream_t stream) {
    const float* xs   = (const float*)d_in[0];
    const float* Wih0 = (const float*)d_in[1];
    const float* Whh0 = (const float*)d_in[2];
    const float* bih0 = (const float*)d_in[3];
    const float* bhh0 = (const float*)d_in[4];
    const float* Wih1 = (const float*)d_in[5];
    const float* Whh1 = (const float*)d_in[6];
    const float* bih1 = (const float*)d_in[7];
    const float* bhh1 = (const float*)d_in[8];
    const float* Wout = (const float*)d_in[9];
    const float* bout = (const float*)d_in[10];
    float* out = (float*)d_out;

    char* ws = (char*)d_ws;
    size_t off = 0;
    bf16* xs_pad = (bf16*)(ws + off); off += (size_t)T_STEPS * B_SZ * XK * 2;
    bf16* Wc0    = (bf16*)(ws + off); off += (size_t)N0PAD * K0 * 2;
    bf16* Wc1    = (bf16*)(ws + off); off += (size_t)N1PAD * K1 * 2;
    float* b0    = (float*)(ws + off); off += (size_t)N0PAD * 4;
    float* b1    = (float*)(ws + off); off += (size_t)N1PAD * 4;
    bf16* Sring  = (bf16*)(ws + off); off += (size_t)8 * RING * SLAB * 2;
    int*  flags  = (int*)(ws + off);  off += (size_t)16 * FSTR * 4;

    // ring (incl. zero-state slots + pad columns) and all flag slots start zero
    hipMemsetAsync(Sring, 0, (size_t)8 * RING * SLAB * 2, stream);
    hipMemsetAsync(flags, 0, (size_t)16 * FSTR * 4, stream);

    prep_xs <<<(T_STEPS * B_SZ * XK + 255) / 256, 256, 0, stream>>>(xs, xs_pad);
    pack_w0 <<<(N0PAD * K0 + 255) / 256, 256, 0, stream>>>(Wih0, Whh0, Wc0);
    pack_w1 <<<(N1PAD * K1 + 255) / 256, 256, 0, stream>>>(Wih1, Whh1, Wc1);
    pack_bias<<<(N0PAD + 255) / 256, 256, 0, stream>>>(bih0, bhh0, b0, N0PAD);
    pack_bias<<<(N1PAD + 255) / 256, 256, 0, stream>>>(bih1, bhh1, b1, N1PAD);

    // dynamic LDS: max(W0 slice 147456 B, W1 slice 129024 B)
    hipFuncSetAttribute((const void*)persist,
                        hipFuncAttributeMaxDynamicSharedMemorySize, 147456);
    void* args[] = { (void*)&xs_pad, (void*)&Wc0, (void*)&Wc1, (void*)&b0,
                     (void*)&b1, (void*)&Sring, (void*)&flags };
    hipLaunchCooperativeKernel((const void*)persist, dim3(NBLK), dim3(512),
                               args, 147456, stream);

    classifier<<<B_SZ / 4, 256, 0, stream>>>(Sring, Wout, bout, out);
}

// Round 23
// 1604.491 us; speedup vs baseline: 1.2131x; 1.0038x over previous
//
#include <hip/hip_runtime.h>
#include <hip/hip_bf16.h>

#define T_STEPS 128
#define B_SZ    1024
#define IN_SZ   47
#define H_SZ    646
#define OUT_SZ  5

#define XK    96      // xs padded row stride (47 -> 96)
#define K0    768     // layer0 K = 96 + 672
#define K1    1344    // layer1 K = 672 + 672 (also the state-slab row stride)
#define N0PAD 704     // L0 packed-W cols (11 * 64, zero-padded)
#define N1PAD 672     // L1 packed-W cols
#define RING  17      // RING=6 L2-resident ring falsified (r15 3310us fenced,
                      // r16 4423us XCD-pinned). 17-slot MALL-resident ring +
                      // spread readers + fresh-address eviction is fastest.
#define SLAB  172032  // 128 rows * 1344 cols, elements per rg slab
#define FSTR  256     // flag GROUP stride (ints); per-publisher slots
#define SLOT  16      // ints between publisher slots (64B, no line sharing)

// tiles (r11-proven): L0 96-col x7 blocks, L1 48-col x14 blocks
#define NL0B  7
#define NL1B  14
#define NBLK  (8 * (NL0B + NL1B))   // 168

typedef __hip_bfloat16 bf16;
typedef unsigned short ush;
using frag8 = __attribute__((ext_vector_type(8))) short;  // 8 bf16
using f32x4 = __attribute__((ext_vector_type(4))) float;

// ---------------------------------------------------------------- prep kernels

__global__ void prep_xs(const float* __restrict__ xs, bf16* __restrict__ xs_pad) {
    int idx = blockIdx.x * blockDim.x + threadIdx.x;
    if (idx >= T_STEPS * B_SZ * XK) return;
    int k = idx % XK;
    int rb = idx / XK;
    float v = (k < IN_SZ) ? xs[(size_t)rb * IN_SZ + k] : 0.f;
    xs_pad[idx] = __float2bfloat16(v);
}

__global__ void pack_w0(const float* __restrict__ Wih, const float* __restrict__ Whh,
                        bf16* __restrict__ Wc) {
    int idx = blockIdx.x * blockDim.x + threadIdx.x;
    if (idx >= N0PAD * K0) return;
    int j = idx / K0, k = idx % K0;
    float v = 0.f;
    if (j < H_SZ) {
        if (k < IN_SZ)                      v = Wih[(size_t)j * IN_SZ + k];
        else if (k >= XK && k < XK + H_SZ)  v = Whh[(size_t)j * H_SZ + (k - XK)];
    }
    Wc[idx] = __float2bfloat16(v);
}

__global__ void pack_w1(const float* __restrict__ Wih, const float* __restrict__ Whh,
                        bf16* __restrict__ Wc) {
    int idx = blockIdx.x * blockDim.x + threadIdx.x;
    if (idx >= N1PAD * K1) return;
    int j = idx / K1, k = idx % K1;
    float v = 0.f;
    if (j < H_SZ) {
        if (k < H_SZ)                          v = Wih[(size_t)j * H_SZ + k];
        else if (k >= 672 && k < 672 + H_SZ)   v = Whh[(size_t)j * H_SZ + (k - 672)];
    }
    Wc[idx] = __float2bfloat16(v);
}

__global__ void pack_bias(const float* __restrict__ bi, const float* __restrict__ bh,
                          float* __restrict__ b, int n) {
    int j = blockIdx.x * blockDim.x + threadIdx.x;
    if (j >= n) return;
    b[j] = (j < H_SZ) ? (bi[j] + bh[j]) : 0.f;
}

// ---------------------------------------------------------------- persistent RNN
// FINAL == r18 (harness-verified twice: 1607us round 8, 1610us round 22;
// replay-proven). Session ledger — all single-variable probes from this
// structure, measured on MI355X:
//  * RING=6 L2-resident ring: 2-3x SLOWER (r15 fenced 3310us, r16 pinned
//    4423us) — concentrating 21 streaming readers thrashes one 4MB L2.
//  * per-step agent acquire/release fences: +14us/step (r15) — wbl2 drains.
//  * flag RMW decontention + lane-parallel polls: neutral (r18, kept).
//  * wave-granular barrier-free protocol: neutral AND intermittently racy
//    (r20 post-timing divergence) — WITHDRAWN.
//  * VGPR pin via waves_per_eu: no gain (r20).
//  * NON-TEMPORAL h stores: +315us (r22) — WRITE_SIZE 337->655MB (partial-
//    line write-through), FETCH unchanged (no dirty-line tail existed);
//    store-ack latency moved ONTO the serial chain's pre-publish drain.
// Net: the ~6us serial hop (256 hops = 128 steps x 2 layers) is invariant
// to state placement, flag contention, barrier granularity, and register
// budget. W1 (1.8MB) >> LDS (160KB) forces the >=12-way column split that
// makes the per-step all-to-all exchange intrinsic; per-instruction models
// give ~3us/hop, residual is unattributed MALL-exchange latency. Further
// progress needs a different decomposition or instruction-level latency
// probes beyond this harness.
// Structure: r13 skeleton (column tiles, W-in-LDS, plain dirty-L2 h-state
// stores, 17-slot ring, per-wrap agent-acquire fence, publish after
// __syncthreads vmcnt drain) + L1 h0-before-h1 critical-path order +
// per-publisher flag slots with lane-parallel observation.

__device__ __forceinline__ void tanh_store(ush* dst, float x) {
    x = fminf(fmaxf(x, -15.f), 15.f);
    float e = __expf(2.f * x);
    bf16 hb = __float2bfloat16((e - 1.f) / (e + 1.f));
    *dst = *(ush*)&hb;     // plain store: coalesced, dirty in local (XCD) L2
}

__device__ __forceinline__ void poll_ge(int* p, int need) {
    while (__hip_atomic_load(p, __ATOMIC_RELAXED, __HIP_MEMORY_SCOPE_AGENT) < need)
        __builtin_amdgcn_s_sleep(2);
}

__global__ __launch_bounds__(512, 2) void persist(
    const bf16* __restrict__ xs_pad, const bf16* __restrict__ Wc0,
    const bf16* __restrict__ Wc1, const float* __restrict__ b0,
    const float* __restrict__ b1, bf16* __restrict__ Sring,
    int* __restrict__ flags)
{
    extern __shared__ ush Wlds[];
    const int bid  = blockIdx.x;
    const int rg   = bid & 7;
    const int c8   = bid >> 3;
    const bool isL0 = (c8 < NL0B);
    const int tid  = threadIdx.x;
    const int wv   = tid >> 6;
    const int lane = tid & 63;
    const int q8   = (lane >> 4) * 8;    // fragment k offset (elements)
    const int l15  = lane & 15;

    // ---- stage W slice into LDS in fragment order (once) ----
    if (isL0) {
        const int col0 = c8 * 96;
        for (int g = wv; g < 144; g += 8) {           // g = kc*6 + ct
            int kc = g / 6, ct = g % 6;
            const bf16* src = Wc0 + (size_t)(col0 + ct*16 + l15) * K0 + kc*32 + q8;
            *(uint4*)&Wlds[g*512 + lane*8] = *(const uint4*)src;
        }
    } else {
        const int col0 = (c8 - NL0B) * 48;
        for (int g = wv; g < 126; g += 8) {           // g = kc*3 + ct
            int kc = g / 3, ct = g % 3;
            const bf16* src = Wc1 + (size_t)(col0 + ct*16 + l15) * K1 + kc*32 + q8;
            *(uint4*)&Wlds[g*512 + lane*8] = *(const uint4*)src;
        }
    }
    __syncthreads();

    const int loc = wv * 16 + l15;      // this wave's A-fragment row (16 rows/wave)
    bf16* const ringbase = Sring + (size_t)rg * RING * SLAB;
    int*  const fL0 = flags + rg * FSTR;          // NL0B publisher slots (SLOT apart)
    int*  const fL1 = flags + (8 + rg) * FSTR;    // NL1B publisher slots

    if (isL0) {
        const int col0 = c8 * 96;
        float bias[6];
        #pragma unroll
        for (int ct = 0; ct < 6; ++ct) bias[ct] = b0[col0 + ct*16 + l15];

        for (int p = 0; p < 128; ++p) {
            const bf16* rsl = ringbase + (size_t)((p + RING - 1) % RING) * SLAB;
            bf16*       wsl = ringbase + (size_t)(p % RING) * SLAB;

            // xs chunks: input-static, issue before any wait
            const bf16* xr = xs_pad + ((size_t)p * B_SZ + rg*128 + loc) * XK + q8;
            uint4 xbuf[3];
            #pragma unroll
            for (int i = 0; i < 3; ++i) xbuf[i] = *(const uint4*)(xr + i*32);

            // parallel poll: lanes 0..6 watch L0 slots; lanes 16..29 watch L1
            // slots (WAR). One converged loop -> all slots observed in parallel.
            if (wv == 0) {
                int* addr = nullptr; int need = 0;
                if (p > 0 && lane < NL0B)            { addr = &fL0[lane * SLOT];        need = p; }
                else if (p >= RING && lane >= 16 && lane < 16 + NL1B)
                                                     { addr = &fL1[(lane - 16) * SLOT]; need = p - 16; }
                if (addr) poll_ge(addr, need);
            }
            __syncthreads();
            if (p >= RING + 1 && (p - 1) % RING == 0)
                __builtin_amdgcn_fence(__ATOMIC_ACQUIRE, "agent");

            // A = [x_t(96) | h0(p-1)(672)], C = h0(p) -> slab cols [0,672)
            const bf16* hr = rsl + (size_t)loc * K1 + q8;
            uint4 hbuf[21];
            #pragma unroll
            for (int i = 0; i < 21; ++i) hbuf[i] = *(const uint4*)(hr + i*32);

            f32x4 acc[6] = {};
            #pragma unroll
            for (int kc = 0; kc < 24; ++kc) {
                frag8 af = (kc < 3) ? *(const frag8*)&xbuf[kc]
                                    : *(const frag8*)&hbuf[kc-3];
                #pragma unroll
                for (int ct = 0; ct < 6; ++ct) {
                    frag8 wf = *(const frag8*)&Wlds[(kc*6+ct)*512 + lane*8];
                    acc[ct] = __builtin_amdgcn_mfma_f32_16x16x32_bf16(
                        af, wf, acc[ct], 0, 0, 0);
                }
            }
            const int rbase = wv*16 + (lane>>4)*4;
            #pragma unroll
            for (int ct = 0; ct < 6; ++ct) {
                const int col = col0 + ct*16 + l15;
                if (col < H_SZ) {
                    #pragma unroll
                    for (int i = 0; i < 4; ++i)
                        tanh_store((ush*)(wsl + (size_t)(rbase+i)*K1 + col),
                                   acc[ct][i] + bias[ct]);
                }
            }
            __syncthreads();   // per-wave vmcnt(0) drain: stores in L2 pre-publish
            if (tid == 0)
                __hip_atomic_store(&fL0[c8 * SLOT], p + 1, __ATOMIC_RELAXED,
                                   __HIP_MEMORY_SCOPE_AGENT);
        }
    } else {
        const int col0 = (c8 - NL0B) * 48;
        const int myslot = (c8 - NL0B) * SLOT;
        float bias[3];
        #pragma unroll
        for (int ct = 0; ct < 3; ++ct) bias[ct] = b1[col0 + ct*16 + l15];

        for (int q = 1; q <= 128; ++q) {
            const bf16* rsl = ringbase + (size_t)((q + RING - 1) % RING) * SLAB;
            bf16*       wsl = ringbase + (size_t)(q % RING) * SLAB;
            const bf16* ar  = rsl + (size_t)loc * K1 + q8;

            // ---- stage 1: h0 half (gated only by fL0; L0 runs ~15 ahead) ----
            if (wv == 0 && lane < NL0B) poll_ge(&fL0[lane * SLOT], q);
            __syncthreads();
            if (q >= RING + 1 && (q - 1) % RING == 0)
                __builtin_amdgcn_fence(__ATOMIC_ACQUIRE, "agent");

            uint4 h0buf[21];
            #pragma unroll
            for (int i = 0; i < 21; ++i) h0buf[i] = *(const uint4*)(ar + i*32);
            f32x4 acc[3] = {};
            #pragma unroll
            for (int kc = 0; kc < 21; ++kc) {
                frag8 af = *(const frag8*)&h0buf[kc];
                #pragma unroll
                for (int ct = 0; ct < 3; ++ct) {
                    frag8 wf = *(const frag8*)&Wlds[(kc*3+ct)*512 + lane*8];
                    acc[ct] = __builtin_amdgcn_mfma_f32_16x16x32_bf16(
                        af, wf, acc[ct], 0, 0, 0);
                }
            }

            // ---- stage 2: h1 half (the true serial gate, polled LATE) ----
            if (q > 1) {
                if (wv == 0 && lane < NL1B) poll_ge(&fL1[lane * SLOT], q - 1);
                __syncthreads();
            }
            uint4 h1buf[21];
            #pragma unroll
            for (int i = 0; i < 21; ++i)
                h1buf[i] = *(const uint4*)(ar + (21 + i)*32);
            #pragma unroll
            for (int kc = 21; kc < 42; ++kc) {
                frag8 af = *(const frag8*)&h1buf[kc-21];
                #pragma unroll
                for (int ct = 0; ct < 3; ++ct) {
                    frag8 wf = *(const frag8*)&Wlds[(kc*3+ct)*512 + lane*8];
                    acc[ct] = __builtin_amdgcn_mfma_f32_16x16x32_bf16(
                        af, wf, acc[ct], 0, 0, 0);
                }
            }
            const int rbase = wv*16 + (lane>>4)*4;
            #pragma unroll
            for (int ct = 0; ct < 3; ++ct) {
                const int col = col0 + ct*16 + l15;
                if (col < H_SZ) {
                    #pragma unroll
                    for (int i = 0; i < 4; ++i)
                        tanh_store((ush*)(wsl + (size_t)(rbase+i)*K1 + 672 + col),
                                   acc[ct][i] + bias[ct]);
                }
            }
            __syncthreads();   // per-wave vmcnt(0) drain: stores in L2 pre-publish
            if (tid == 0)
                __hip_atomic_store(&fL1[myslot], q, __ATOMIC_RELAXED,
                                   __HIP_MEMORY_SCOPE_AGENT);
        }
    }
}

// ---------------------------------------------------------------- classifier
__global__ __launch_bounds__(256) void classifier(
    const bf16* __restrict__ Sring, const float* __restrict__ Wout,
    const float* __restrict__ bout, float* __restrict__ out)
{
    const int wave = threadIdx.x >> 6, lane = threadIdx.x & 63;
    const int row = blockIdx.x * 4 + wave;
    const int rg = row >> 7, loc = row & 127;
    const bf16* h1 = Sring + ((size_t)rg * RING + (128 % RING)) * SLAB
                     + (size_t)loc * K1 + 672;
    float acc[OUT_SZ] = {0.f, 0.f, 0.f, 0.f, 0.f};
    for (int k = lane; k < H_SZ; k += 64) {
        float h = __bfloat162float(h1[k]);
        #pragma unroll
        for (int o = 0; o < OUT_SZ; ++o) acc[o] += h * Wout[(size_t)o * H_SZ + k];
    }
    #pragma unroll
    for (int o = 0; o < OUT_SZ; ++o) {
        float v = acc[o];
        #pragma unroll
        for (int off = 32; off; off >>= 1) v += __shfl_down(v, off, 64);
        if (lane == 0) out[(size_t)row * OUT_SZ + o] = v + bout[o];
    }
}

// ---------------------------------------------------------------- launch

extern "C" void kernel_launch(void* const* d_in, const int* in_sizes, int n_in,
                              void* d_out, int out_size, void* d_ws, size_t ws_size,
                              hipStream_t stream) {
    const float* xs   = (const float*)d_in[0];
    const float* Wih0 = (const float*)d_in[1];
    const float* Whh0 = (const float*)d_in[2];
    const float* bih0 = (const float*)d_in[3];
    const float* bhh0 = (const float*)d_in[4];
    const float* Wih1 = (const float*)d_in[5];
    const float* Whh1 = (const float*)d_in[6];
    const float* bih1 = (const float*)d_in[7];
    const float* bhh1 = (const float*)d_in[8];
    const float* Wout = (const float*)d_in[9];
    const float* bout = (const float*)d_in[10];
    float* out = (float*)d_out;

    char* ws = (char*)d_ws;
    size_t off = 0;
    bf16* xs_pad = (bf16*)(ws + off); off += (size_t)T_STEPS * B_SZ * XK * 2;
    bf16* Wc0    = (bf16*)(ws + off); off += (size_t)N0PAD * K0 * 2;
    bf16* Wc1    = (bf16*)(ws + off); off += (size_t)N1PAD * K1 * 2;
    float* b0    = (float*)(ws + off); off += (size_t)N0PAD * 4;
    float* b1    = (float*)(ws + off); off += (size_t)N1PAD * 4;
    bf16* Sring  = (bf16*)(ws + off); off += (size_t)8 * RING * SLAB * 2;
    int*  flags  = (int*)(ws + off);  off += (size_t)16 * FSTR * 4;

    // ring (incl. zero-state slots + pad columns) and all flag slots start zero
    hipMemsetAsync(Sring, 0, (size_t)8 * RING * SLAB * 2, stream);
    hipMemsetAsync(flags, 0, (size_t)16 * FSTR * 4, stream);

    prep_xs <<<(T_STEPS * B_SZ * XK + 255) / 256, 256, 0, stream>>>(xs, xs_pad);
    pack_w0 <<<(N0PAD * K0 + 255) / 256, 256, 0, stream>>>(Wih0, Whh0, Wc0);
    pack_w1 <<<(N1PAD * K1 + 255) / 256, 256, 0, stream>>>(Wih1, Whh1, Wc1);
    pack_bias<<<(N0PAD + 255) / 256, 256, 0, stream>>>(bih0, bhh0, b0, N0PAD);
    pack_bias<<<(N1PAD + 255) / 256, 256, 0, stream>>>(bih1, bhh1, b1, N1PAD);

    // dynamic LDS: max(W0 slice 147456 B, W1 slice 129024 B)
    hipFuncSetAttribute((const void*)persist,
                        hipFuncAttributeMaxDynamicSharedMemorySize, 147456);
    void* args[] = { (void*)&xs_pad, (void*)&Wc0, (void*)&Wc1, (void*)&b0,
                     (void*)&b1, (void*)&Sring, (void*)&flags };
    hipLaunchCooperativeKernel((const void*)persist, dim3(NBLK), dim3(512),
                               args, 147456, stream);

    classifier<<<B_SZ / 4, 256, 0, stream>>>(Sring, Wout, bout, out);
}